// Round 3
// baseline (101.737 us; speedup 1.0000x reference)
//
#include <hip/hip_runtime.h>
#include <math.h>

#define kNB 16
#define kNA 5
#define kNH 128
#define kNW 128
#define kMaxT 50
#define kNC 20
#define kCH 26
#define kRowW 33
#define kNTot (kNB*kNA*kNH*kNW)         // 1,310,720
#define DENSE_BLOCKS 2048
#define kStride (DENSE_BLOCKS * 256)    // 524,288 threads
#define TOT_F4 (kNTot * kCH / 4)        // 8,519,680 float4s, exact

// ws layout (doubles):
// 0 S_all  1 nProposals  2 S_excl  3 cnt_excl  4 nM  5 bce_mask
// 6 sx 7 sy 8 sw 9 sh  10 ce_sum  11 nGT  12 nCorrect  13 block-done counter (uint)

__device__ __forceinline__ float softplus_fast(float x) {
    return fmaxf(x, 0.0f) + __logf(1.0f + __expf(-fabsf(x)));
}
__device__ __forceinline__ float softplusf(float x) {   // precise, for sparse terms
    return fmaxf(x, 0.0f) + log1pf(expf(-fabsf(x)));
}

__device__ __forceinline__ double wave_sum(double v) {
    #pragma unroll
    for (int off = 32; off > 0; off >>= 1) v += __shfl_down(v, off, 64);
    return v;
}

__device__ __forceinline__ float inv_tanhf(float y) {
    float yc = fminf(fmaxf(y, -1.0f + 1e-6f), 1.0f - 1e-6f);
    float v = 0.5f * logf((1.0f + yc) / (1.0f - yc));
    return (y <= -1.0f) ? -2.0f : ((y >= 1.0f) ? 2.0f : v);
}

// branchless conf extraction from one float4 at float4-index with residue r=(4*idx)%26
__device__ __forceinline__ void conf_step(const float4 v, int r, float& sp, int& prop) {
    float p = (r == 0) ? v.x : ((r == 25) ? v.y : ((r == 24) ? v.z : v.w));
    bool has = (r == 0) | (r >= 23);
    float s = softplus_fast(p);
    sp += has ? s : 0.0f;
    prop += (has & (p > 0.0f)) ? 1 : 0;
}

extern "C" __global__ __launch_bounds__(256)
void yolo_main(const float* __restrict__ pred, const float* __restrict__ target,
               const int* __restrict__ tsizes, const float* __restrict__ anchors,
               double* __restrict__ ws, float* __restrict__ out)
{
    const int tid = threadIdx.x;

    if (blockIdx.x >= kNB) {
        // ============ dense conf stream: branchless, unrolled, coalesced ============
        __shared__ double s_red[8];
        const float4* __restrict__ p4 = (const float4*)pred;
        const int t0 = (int)(blockIdx.x - kNB) * 256 + tid;   // < kStride
        int r = (4 * t0) % 26;
        float sp = 0.0f;
        int prop = 0;
        int idx = t0;
        #pragma unroll 4
        for (int k = 0; k < 16; ++k) {          // 16*kStride = 8,388,608 <= TOT_F4
            float4 v = p4[idx];
            conf_step(v, r, sp, prop);
            idx += kStride;
            r += 18;                            // (4*kStride) % 26 == 18
            r = (r >= 26) ? r - 26 : r;
        }
        if (idx < TOT_F4)                       // tail: 131,072 float4s
            conf_step(p4[idx], r, sp, prop);

        double spd = wave_sum((double)sp);
        double prd = wave_sum((double)prop);
        int wid = tid >> 6;
        if ((tid & 63) == 0) { s_red[wid] = spd; s_red[4 + wid] = prd; }
        __syncthreads();
        if (tid == 0) {
            atomicAdd(&ws[0], s_red[0] + s_red[1] + s_red[2] + s_red[3]);
            atomicAdd(&ws[1], s_red[4] + s_red[5] + s_red[6] + s_red[7]);
        }
    } else {
        // ============ sparse targets part (one block per batch) ============
        const int b = blockIdx.x;
        __shared__ float s_t[kMaxT][kRowW];
        __shared__ float s_aw[kNA], s_ah[kNA];
        __shared__ int s_cell[kMaxT], s_bn[kMaxT], s_zm[kMaxT], s_valid[kMaxT];
        __shared__ int s_label[kMaxT];
        __shared__ float s_tx[kMaxT], s_ty[kMaxT], s_tw[kMaxT], s_th[kMaxT];

        for (int i = tid; i < kMaxT * kRowW; i += 256)
            ((float*)s_t)[i] = target[(long long)b * kMaxT * kRowW + i];
        if (tid < kNA) {
            s_aw[tid] = anchors[tid * 2 + 0] / 8.0f;
            s_ah[tid] = anchors[tid * 2 + 1] / 8.0f;
        }
        __syncthreads();

        const int tsz = tsizes[b];
        double ngt = 0.0, ncorr = 0.0;
        int myCell = -1;

        if (tid < kMaxT) {
            const float* row = s_t[tid];
            float gx = row[0] / 8.0f, gy = row[1] / 8.0f;
            float gh = row[3] / 8.0f, gw = row[4] / 8.0f;
            int valid = (tid < tsz) && (gw != 0.0f) && (gh != 0.0f);
            int gi = min(max((int)gx, 0), kNW - 1);
            int gj = min(max((int)gy, 0), kNH - 1);

            float best = -1.0f; int bn = 0; int zm = 0;
            #pragma unroll
            for (int a = 0; a < kNA; ++a) {
                float aw = s_aw[a], ah = s_ah[a];
                float inter = fmaxf(fminf(gw, aw) + 1.0f, 0.0f) * fmaxf(fminf(gh, ah) + 1.0f, 0.0f);
                float iou = inter / ((gw + 1.0f) * (gh + 1.0f) + (aw + 1.0f) * (ah + 1.0f) - inter + 1e-16f);
                if (iou > best) { best = iou; bn = a; }
                if (iou > 0.5f) zm |= (1 << a);
            }

            int lab = 0; float lbest = row[13];
            #pragma unroll
            for (int c = 1; c < kNC; ++c)
                if (row[13 + c] > lbest) { lbest = row[13 + c]; lab = c; }

            long long base = ((((long long)b * kNA + bn) * kNH + gj) * kNW + gi) * kCH;
            float pc = pred[base + 0];
            float px = tanhf(pred[base + 1]) + 0.5f + (float)gi;
            float py = tanhf(pred[base + 2]) + 0.5f + (float)gj;
            float ph = expf(pred[base + 4]) * s_ah[bn];
            float pw = expf(pred[base + 5]) * s_aw[bn];
            float b1x1 = gx - gw, b1x2 = gx + gw, b1y1 = gy - gh, b1y2 = gy + gh;
            float b2x1 = px - pw, b2x2 = px + pw, b2y1 = py - ph, b2y2 = py + ph;
            float iw = fmaxf(fminf(b1x2, b2x2) - fmaxf(b1x1, b2x1) + 1.0f, 0.0f);
            float ih = fmaxf(fminf(b1y2, b2y2) - fmaxf(b1y1, b2y1) + 1.0f, 0.0f);
            float inter2 = iw * ih;
            float a1 = (b1x2 - b1x1 + 1.0f) * (b1y2 - b1y1 + 1.0f);
            float a2 = (b2x2 - b2x1 + 1.0f) * (b2y2 - b2y1 + 1.0f);
            float iou2 = inter2 / (a1 + a2 - inter2 + 1e-16f);
            int plab = 0; float pbest = pred[base + 6];
            #pragma unroll
            for (int c = 1; c < kNC; ++c) {
                float v = pred[base + 6 + c];
                if (v > pbest) { pbest = v; plab = c; }
            }
            int correct = valid && (iou2 > 0.5f) && (plab == lab) && (pc > 0.0f);

            myCell = gj * kNW + gi;
            s_cell[tid] = myCell; s_bn[tid] = bn; s_zm[tid] = zm; s_valid[tid] = valid;
            s_label[tid] = lab;
            s_tx[tid] = inv_tanhf(gx - ((float)gi + 0.5f));
            s_ty[tid] = inv_tanhf(gy - ((float)gj + 0.5f));
            s_tw[tid] = logf(gw / s_aw[bn] + 1e-16f);
            s_th[tid] = logf(gh / s_ah[bn] + 1e-16f);
            ngt = (double)valid; ncorr = (double)correct;
        }
        __syncthreads();

        // lane-parallel last-writer-wins resolution
        double S_excl = 0, cnt_excl = 0, nM = 0, bce = 0;
        double sx = 0, sy = 0, sw_ = 0, sh_ = 0, ce = 0;

        if (tid < kMaxT) {
            int lastTouch[kNA], lastSet[kNA], lastCm[kNA];
            #pragma unroll
            for (int a = 0; a < kNA; ++a) { lastTouch[a] = -1; lastSet[a] = -1; lastCm[a] = 0; }

            for (int tp = 0; tp < kMaxT; ++tp) {
                if (!s_valid[tp] || s_cell[tp] != myCell) continue;
                int bnp = s_bn[tp], zmp = s_zm[tp];
                #pragma unroll
                for (int a = 0; a < kNA; ++a) {
                    bool setr = (bnp == a);
                    if (setr || ((zmp >> a) & 1)) { lastTouch[a] = tp; lastCm[a] = setr ? 1 : 0; }
                    if (setr) lastSet[a] = tp;
                }
            }

            int gj = myCell >> 7, gi = myCell & 127;
            #pragma unroll
            for (int a = 0; a < kNA; ++a) {
                if (lastTouch[a] != tid) continue;          // unique owner per (cell,a)
                bool msk = lastSet[a] >= 0;
                bool cmf = lastCm[a] != 0;
                if (!msk && cmf) continue;
                long long base = ((((long long)b * kNA + a) * kNH + gj) * kNW + gi) * kCH;
                float pc = pred[base];
                float sp2 = softplusf(pc);
                S_excl += (double)sp2; cnt_excl += 1.0;
                if (msk) {
                    int ts = lastSet[a];
                    nM += 1.0; bce += (double)(sp2 - pc);
                    float dx = pred[base + 1] - s_tx[ts];
                    float dy = pred[base + 2] - s_ty[ts];
                    float dh = pred[base + 4] - s_th[ts];
                    float dw = pred[base + 5] - s_tw[ts];
                    sx += (double)(dx * dx); sy += (double)(dy * dy);
                    sw_ += (double)(dw * dw); sh_ += (double)(dh * dh);
                    float m20 = pred[base + 6];
                    #pragma unroll
                    for (int c = 1; c < kNC; ++c) m20 = fmaxf(m20, pred[base + 6 + c]);
                    float es = 0.0f;
                    #pragma unroll
                    for (int c = 0; c < kNC; ++c) es += expf(pred[base + 6 + c] - m20);
                    ce += (double)(m20 + logf(es) - pred[base + 6 + s_label[ts]]);
                }
            }
        }

        if (tid < 64) {
            S_excl = wave_sum(S_excl); cnt_excl = wave_sum(cnt_excl);
            nM = wave_sum(nM); bce = wave_sum(bce);
            sx = wave_sum(sx); sy = wave_sum(sy); sw_ = wave_sum(sw_); sh_ = wave_sum(sh_);
            ce = wave_sum(ce); ngt = wave_sum(ngt); ncorr = wave_sum(ncorr);
            if (tid == 0) {
                atomicAdd(&ws[2], S_excl); atomicAdd(&ws[3], cnt_excl);
                atomicAdd(&ws[4], nM);     atomicAdd(&ws[5], bce);
                atomicAdd(&ws[6], sx);     atomicAdd(&ws[7], sy);
                atomicAdd(&ws[8], sw_);    atomicAdd(&ws[9], sh_);
                atomicAdd(&ws[10], ce);    atomicAdd(&ws[11], ngt);
                atomicAdd(&ws[12], ncorr);
            }
        }
    }

    // ============ last-block finalize (device-scope) ============
    if (tid == 0) {
        __threadfence();
        unsigned int* cnt = (unsigned int*)&ws[13];
        unsigned int done = atomicAdd(cnt, 1u);
        if (done == (unsigned)(DENSE_BLOCKS + kNB - 1)) {
            // atomic reads: guaranteed to see all device-scope atomics
            double S_all   = atomicAdd(&ws[0], 0.0);
            double nProp   = atomicAdd(&ws[1], 0.0);
            double S_excl  = atomicAdd(&ws[2], 0.0);
            double cntex   = atomicAdd(&ws[3], 0.0);
            double nMc     = atomicAdd(&ws[4], 0.0);
            double bce     = atomicAdd(&ws[5], 0.0);
            double sx      = atomicAdd(&ws[6], 0.0);
            double sy      = atomicAdd(&ws[7], 0.0);
            double sw2     = atomicAdd(&ws[8], 0.0);
            double sh2     = atomicAdd(&ws[9], 0.0);
            double ce      = atomicAdd(&ws[10], 0.0);
            double nGT     = atomicAdd(&ws[11], 0.0);
            double nCorr   = atomicAdd(&ws[12], 0.0);
            double nM = fmax(nMc, 1.0);
            double nF = fmax((double)kNTot - cntex, 1.0);
            double loss_conf = 1.25 * (S_all - S_excl) / nF + bce / nM;
            double loss = (sx + sy + sw2 + sh2) / nM + loss_conf + (ce / nM) / 16.0;
            double recall = (nGT > 0.0) ? nCorr / fmax(nGT, 1.0) : 1.0;
            double precision = (nProp > 0.0) ? nCorr / fmax(nProp, 1.0) : 1.0;
            out[0] = (float)loss;
            out[1] = (float)recall;
            out[2] = (float)precision;
        }
    }
}

extern "C" void kernel_launch(void* const* d_in, const int* in_sizes, int n_in,
                              void* d_out, int out_size, void* d_ws, size_t ws_size,
                              hipStream_t stream) {
    const float* pred    = (const float*)d_in[0];
    const float* target  = (const float*)d_in[1];
    const int*   tsizes  = (const int*)d_in[2];
    const float* anchors = (const float*)d_in[3];
    float* out = (float*)d_out;
    double* ws = (double*)d_ws;

    hipMemsetAsync(d_ws, 0, 14 * sizeof(double), stream);
    yolo_main<<<DENSE_BLOCKS + kNB, 256, 0, stream>>>(pred, target, tsizes, anchors, ws, out);
}

// Round 4
// 52.098 us; speedup vs baseline: 1.9528x; 1.9528x over previous
//
#include <hip/hip_runtime.h>
#include <math.h>

#define kNB 16
#define kNA 5
#define kNH 128
#define kNW 128
#define kMaxT 50
#define kNC 20
#define kCH 26
#define kRowW 33
#define kNTot (kNB*kNA*kNH*kNW)         // 1,310,720
#define DENSE_BLOCKS 2048
#define kStride (DENSE_BLOCKS * 256)    // 524,288 threads
#define TOT_F4 (kNTot * kCH / 4)        // 8,519,680 float4s, exact

// ws layout (doubles):
// [0..12] sparse accumulators (atomics from 16 target blocks):
//   0 unused  1 unused  2 S_excl  3 cnt_excl  4 nM  5 bce_mask
//   6 sx 7 sy 8 sw 9 sh  10 ce_sum  11 nGT  12 nCorrect
// [16 .. 16+2047]            per-block dense softplus partials
// [16+2048 .. 16+4095]       per-block dense proposal-count partials

__device__ __forceinline__ float softplus_fast(float x) {
    return fmaxf(x, 0.0f) + __logf(1.0f + __expf(-fabsf(x)));
}
__device__ __forceinline__ float softplusf(float x) {   // precise, for sparse terms
    return fmaxf(x, 0.0f) + log1pf(expf(-fabsf(x)));
}

__device__ __forceinline__ double wave_sum(double v) {
    #pragma unroll
    for (int off = 32; off > 0; off >>= 1) v += __shfl_down(v, off, 64);
    return v;
}

__device__ __forceinline__ float inv_tanhf(float y) {
    float yc = fminf(fmaxf(y, -1.0f + 1e-6f), 1.0f - 1e-6f);
    float v = 0.5f * logf((1.0f + yc) / (1.0f - yc));
    return (y <= -1.0f) ? -2.0f : ((y >= 1.0f) ? 2.0f : v);
}

// branchless conf extraction; r = (4*float4_index) % 26
__device__ __forceinline__ void conf_step(const float4 v, int r, float& sp, int& prop) {
    float p = (r == 0) ? v.x : ((r == 25) ? v.y : ((r == 24) ? v.z : v.w));
    bool has = (r == 0) | (r >= 23);
    float s = softplus_fast(p);
    sp += has ? s : 0.0f;
    prop += (has & (p > 0.0f)) ? 1 : 0;
}

extern "C" __global__ __launch_bounds__(256)
void yolo_main(const float* __restrict__ pred, const float* __restrict__ target,
               const int* __restrict__ tsizes, const float* __restrict__ anchors,
               double* __restrict__ ws)
{
    const int tid = threadIdx.x;

    if (blockIdx.x >= kNB) {
        // ====== dense conf stream: 4 independent loads per group, branchless ======
        __shared__ double s_red[8];
        const int bid = (int)blockIdx.x - kNB;          // 0..2047
        const float4* __restrict__ p4 = (const float4*)pred;
        const int t0 = bid * 256 + tid;                 // < kStride
        const int r0 = (4 * t0) % 26;
        float sp = 0.0f;
        int prop = 0;

        // 18*k mod 26 for k=0..15 (compile-time)
        constexpr int OFF[16] = {0,18,10,2,20,12,4,22,14,6,24,16,8,0,18,10};

        #pragma unroll
        for (int g = 0; g < 4; ++g) {
            const int base = t0 + (4 * g) * kStride;
            // batch 4 independent loads before any use
            float4 v0 = p4[base];
            float4 v1 = p4[base + kStride];
            float4 v2 = p4[base + 2 * kStride];
            float4 v3 = p4[base + 3 * kStride];
            int ra = r0 + OFF[4*g+0]; ra = (ra >= 26) ? ra - 26 : ra;
            int rb = r0 + OFF[4*g+1]; rb = (rb >= 26) ? rb - 26 : rb;
            int rc = r0 + OFF[4*g+2]; rc = (rc >= 26) ? rc - 26 : rc;
            int rd = r0 + OFF[4*g+3]; rd = (rd >= 26) ? rd - 26 : rd;
            conf_step(v0, ra, sp, prop);
            conf_step(v1, rb, sp, prop);
            conf_step(v2, rc, sp, prop);
            conf_step(v3, rd, sp, prop);
        }
        // tail: k=16, offset 18*16 mod 26 = 2
        {
            const int idx = t0 + 16 * kStride;
            if (idx < TOT_F4) {
                int rt = r0 + 2; rt = (rt >= 26) ? rt - 26 : rt;
                conf_step(p4[idx], rt, sp, prop);
            }
        }

        double spd = wave_sum((double)sp);
        double prd = wave_sum((double)prop);
        int wid = tid >> 6;
        if ((tid & 63) == 0) { s_red[wid] = spd; s_red[4 + wid] = prd; }
        __syncthreads();
        if (tid == 0) {
            ws[16 + bid]               = s_red[0] + s_red[1] + s_red[2] + s_red[3];
            ws[16 + DENSE_BLOCKS + bid] = s_red[4] + s_red[5] + s_red[6] + s_red[7];
        }
        return;
    }

    // ================= sparse targets part (one block per batch) =================
    const int b = blockIdx.x;
    __shared__ float s_t[kMaxT][kRowW];
    __shared__ float s_aw[kNA], s_ah[kNA];
    __shared__ int s_cell[kMaxT], s_bn[kMaxT], s_zm[kMaxT], s_valid[kMaxT];
    __shared__ int s_label[kMaxT];
    __shared__ float s_tx[kMaxT], s_ty[kMaxT], s_tw[kMaxT], s_th[kMaxT];

    for (int i = tid; i < kMaxT * kRowW; i += 256)
        ((float*)s_t)[i] = target[(long long)b * kMaxT * kRowW + i];
    if (tid < kNA) {
        s_aw[tid] = anchors[tid * 2 + 0] / 8.0f;
        s_ah[tid] = anchors[tid * 2 + 1] / 8.0f;
    }
    __syncthreads();

    const int tsz = tsizes[b];
    double ngt = 0.0, ncorr = 0.0;
    int myCell = -1;

    if (tid < kMaxT) {
        const float* row = s_t[tid];
        float gx = row[0] / 8.0f, gy = row[1] / 8.0f;
        float gh = row[3] / 8.0f, gw = row[4] / 8.0f;
        int valid = (tid < tsz) && (gw != 0.0f) && (gh != 0.0f);
        int gi = min(max((int)gx, 0), kNW - 1);
        int gj = min(max((int)gy, 0), kNH - 1);

        float best = -1.0f; int bn = 0; int zm = 0;
        #pragma unroll
        for (int a = 0; a < kNA; ++a) {
            float aw = s_aw[a], ah = s_ah[a];
            float inter = fmaxf(fminf(gw, aw) + 1.0f, 0.0f) * fmaxf(fminf(gh, ah) + 1.0f, 0.0f);
            float iou = inter / ((gw + 1.0f) * (gh + 1.0f) + (aw + 1.0f) * (ah + 1.0f) - inter + 1e-16f);
            if (iou > best) { best = iou; bn = a; }
            if (iou > 0.5f) zm |= (1 << a);
        }

        int lab = 0; float lbest = row[13];
        #pragma unroll
        for (int c = 1; c < kNC; ++c)
            if (row[13 + c] > lbest) { lbest = row[13 + c]; lab = c; }

        long long base = ((((long long)b * kNA + bn) * kNH + gj) * kNW + gi) * kCH;
        float pc = pred[base + 0];
        float px = tanhf(pred[base + 1]) + 0.5f + (float)gi;
        float py = tanhf(pred[base + 2]) + 0.5f + (float)gj;
        float ph = expf(pred[base + 4]) * s_ah[bn];
        float pw = expf(pred[base + 5]) * s_aw[bn];
        float b1x1 = gx - gw, b1x2 = gx + gw, b1y1 = gy - gh, b1y2 = gy + gh;
        float b2x1 = px - pw, b2x2 = px + pw, b2y1 = py - ph, b2y2 = py + ph;
        float iw = fmaxf(fminf(b1x2, b2x2) - fmaxf(b1x1, b2x1) + 1.0f, 0.0f);
        float ih = fmaxf(fminf(b1y2, b2y2) - fmaxf(b1y1, b2y1) + 1.0f, 0.0f);
        float inter2 = iw * ih;
        float a1 = (b1x2 - b1x1 + 1.0f) * (b1y2 - b1y1 + 1.0f);
        float a2 = (b2x2 - b2x1 + 1.0f) * (b2y2 - b2y1 + 1.0f);
        float iou2 = inter2 / (a1 + a2 - inter2 + 1e-16f);
        int plab = 0; float pbest = pred[base + 6];
        #pragma unroll
        for (int c = 1; c < kNC; ++c) {
            float v = pred[base + 6 + c];
            if (v > pbest) { pbest = v; plab = c; }
        }
        int correct = valid && (iou2 > 0.5f) && (plab == lab) && (pc > 0.0f);

        myCell = gj * kNW + gi;
        s_cell[tid] = myCell; s_bn[tid] = bn; s_zm[tid] = zm; s_valid[tid] = valid;
        s_label[tid] = lab;
        s_tx[tid] = inv_tanhf(gx - ((float)gi + 0.5f));
        s_ty[tid] = inv_tanhf(gy - ((float)gj + 0.5f));
        s_tw[tid] = logf(gw / s_aw[bn] + 1e-16f);
        s_th[tid] = logf(gh / s_ah[bn] + 1e-16f);
        ngt = (double)valid; ncorr = (double)correct;
    }
    __syncthreads();

    // lane-parallel last-writer-wins resolution
    double S_excl = 0, cnt_excl = 0, nM = 0, bce = 0;
    double sx = 0, sy = 0, sw_ = 0, sh_ = 0, ce = 0;

    if (tid < kMaxT) {
        int lastTouch[kNA], lastSet[kNA], lastCm[kNA];
        #pragma unroll
        for (int a = 0; a < kNA; ++a) { lastTouch[a] = -1; lastSet[a] = -1; lastCm[a] = 0; }

        for (int tp = 0; tp < kMaxT; ++tp) {
            if (!s_valid[tp] || s_cell[tp] != myCell) continue;
            int bnp = s_bn[tp], zmp = s_zm[tp];
            #pragma unroll
            for (int a = 0; a < kNA; ++a) {
                bool setr = (bnp == a);
                if (setr || ((zmp >> a) & 1)) { lastTouch[a] = tp; lastCm[a] = setr ? 1 : 0; }
                if (setr) lastSet[a] = tp;
            }
        }

        int gj = myCell >> 7, gi = myCell & 127;
        #pragma unroll
        for (int a = 0; a < kNA; ++a) {
            if (lastTouch[a] != tid) continue;          // unique owner per (cell,a)
            bool msk = lastSet[a] >= 0;
            bool cmf = lastCm[a] != 0;
            if (!msk && cmf) continue;
            long long base = ((((long long)b * kNA + a) * kNH + gj) * kNW + gi) * kCH;
            float pc = pred[base];
            float sp2 = softplusf(pc);
            S_excl += (double)sp2; cnt_excl += 1.0;
            if (msk) {
                int ts = lastSet[a];
                nM += 1.0; bce += (double)(sp2 - pc);
                float dx = pred[base + 1] - s_tx[ts];
                float dy = pred[base + 2] - s_ty[ts];
                float dh = pred[base + 4] - s_th[ts];
                float dw = pred[base + 5] - s_tw[ts];
                sx += (double)(dx * dx); sy += (double)(dy * dy);
                sw_ += (double)(dw * dw); sh_ += (double)(dh * dh);
                float m20 = pred[base + 6];
                #pragma unroll
                for (int c = 1; c < kNC; ++c) m20 = fmaxf(m20, pred[base + 6 + c]);
                float es = 0.0f;
                #pragma unroll
                for (int c = 0; c < kNC; ++c) es += expf(pred[base + 6 + c] - m20);
                ce += (double)(m20 + logf(es) - pred[base + 6 + s_label[ts]]);
            }
        }
    }

    if (tid < 64) {
        S_excl = wave_sum(S_excl); cnt_excl = wave_sum(cnt_excl);
        nM = wave_sum(nM); bce = wave_sum(bce);
        sx = wave_sum(sx); sy = wave_sum(sy); sw_ = wave_sum(sw_); sh_ = wave_sum(sh_);
        ce = wave_sum(ce); ngt = wave_sum(ngt); ncorr = wave_sum(ncorr);
        if (tid == 0) {
            atomicAdd(&ws[2], S_excl); atomicAdd(&ws[3], cnt_excl);
            atomicAdd(&ws[4], nM);     atomicAdd(&ws[5], bce);
            atomicAdd(&ws[6], sx);     atomicAdd(&ws[7], sy);
            atomicAdd(&ws[8], sw_);    atomicAdd(&ws[9], sh_);
            atomicAdd(&ws[10], ce);    atomicAdd(&ws[11], ngt);
            atomicAdd(&ws[12], ncorr);
        }
    }
}

extern "C" __global__ __launch_bounds__(256)
void yolo_finalize(const double* __restrict__ ws, float* __restrict__ out) {
    __shared__ double s_red[8];
    const int tid = threadIdx.x;
    double sp = 0.0, pr = 0.0;
    for (int i = tid; i < DENSE_BLOCKS; i += 256) {
        sp += ws[16 + i];
        pr += ws[16 + DENSE_BLOCKS + i];
    }
    sp = wave_sum(sp); pr = wave_sum(pr);
    int wid = tid >> 6;
    if ((tid & 63) == 0) { s_red[wid] = sp; s_red[4 + wid] = pr; }
    __syncthreads();
    if (tid == 0) {
        double S_all = s_red[0] + s_red[1] + s_red[2] + s_red[3];
        double nProp = s_red[4] + s_red[5] + s_red[6] + s_red[7];
        double S_excl = ws[2], cnt_excl = ws[3];
        double nMc = ws[4], bce = ws[5];
        double sx = ws[6], sy = ws[7], sw = ws[8], sh = ws[9], ce = ws[10];
        double nGT = ws[11], nCorr = ws[12];
        double nM = fmax(nMc, 1.0);
        double nF = fmax((double)kNTot - cnt_excl, 1.0);
        double loss_conf = 1.25 * (S_all - S_excl) / nF + bce / nM;
        double loss = (sx + sy + sw + sh) / nM + loss_conf + (ce / nM) / 16.0;
        double recall = (nGT > 0.0) ? nCorr / fmax(nGT, 1.0) : 1.0;
        double precision = (nProp > 0.0) ? nCorr / fmax(nProp, 1.0) : 1.0;
        out[0] = (float)loss;
        out[1] = (float)recall;
        out[2] = (float)precision;
    }
}

extern "C" void kernel_launch(void* const* d_in, const int* in_sizes, int n_in,
                              void* d_out, int out_size, void* d_ws, size_t ws_size,
                              hipStream_t stream) {
    const float* pred    = (const float*)d_in[0];
    const float* target  = (const float*)d_in[1];
    const int*   tsizes  = (const int*)d_in[2];
    const float* anchors = (const float*)d_in[3];
    float* out = (float*)d_out;
    double* ws = (double*)d_ws;

    hipMemsetAsync(d_ws, 0, 16 * sizeof(double), stream);
    yolo_main<<<DENSE_BLOCKS + kNB, 256, 0, stream>>>(pred, target, tsizes, anchors, ws);
    yolo_finalize<<<1, 256, 0, stream>>>(ws, out);
}

// Round 5
// 48.693 us; speedup vs baseline: 2.0894x; 1.0699x over previous
//
#include <hip/hip_runtime.h>
#include <math.h>

#define kNB 16
#define kNA 5
#define kNH 128
#define kNW 128
#define kMaxT 50
#define kNC 20
#define kCH 26
#define kRowW 33
#define kNTot (kNB*kNA*kNH*kNW)         // 1,310,720
#define DENSE_BLOCKS 2048
#define kStride (DENSE_BLOCKS * 256)    // 524,288 threads
#define TOT_F4 (kNTot * kCH / 4)        // 8,519,680 float4s, exact
#define SP_BASE (2 * DENSE_BLOCKS)      // sparse partials start (doubles)
#define SP_N 11                          // partials per sparse block

// ws layout (doubles) — every slot written unconditionally every call (no memset):
// [0..2047]            per-block dense softplus partials
// [2048..4095]         per-block dense proposal-count partials
// [4096..4096+16*11)   per-batch sparse partials:
//   j: 0 S_excl 1 cnt_excl 2 nM 3 bce 4 sx 5 sy 6 sw 7 sh 8 ce 9 nGT 10 nCorrect

__device__ __forceinline__ float softplus_fast(float x) {
    return fmaxf(x, 0.0f) + __logf(1.0f + __expf(-fabsf(x)));
}
__device__ __forceinline__ float softplusf(float x) {   // precise, for sparse terms
    return fmaxf(x, 0.0f) + log1pf(expf(-fabsf(x)));
}

__device__ __forceinline__ double wave_sum(double v) {
    #pragma unroll
    for (int off = 32; off > 0; off >>= 1) v += __shfl_down(v, off, 64);
    return v;
}

__device__ __forceinline__ float inv_tanhf(float y) {
    float yc = fminf(fmaxf(y, -1.0f + 1e-6f), 1.0f - 1e-6f);
    float v = 0.5f * logf((1.0f + yc) / (1.0f - yc));
    return (y <= -1.0f) ? -2.0f : ((y >= 1.0f) ? 2.0f : v);
}

// r = (4*float4_index) % 26 is ALWAYS EVEN -> conf present iff r==0 (lane x) or r==24 (lane z)
__device__ __forceinline__ void conf_step(const float4 v, int r, float& sp, int& prop) {
    bool is0 = (r == 0);
    bool has = is0 | (r == 24);
    float p = is0 ? v.x : v.z;
    float s = softplus_fast(p);
    sp += has ? s : 0.0f;
    prop += (has & (p > 0.0f)) ? 1 : 0;
}

extern "C" __global__ __launch_bounds__(256)
void yolo_main(const float* __restrict__ pred, const float* __restrict__ target,
               const int* __restrict__ tsizes, const float* __restrict__ anchors,
               double* __restrict__ ws)
{
    const int tid = threadIdx.x;

    if (blockIdx.x >= kNB) {
        // ====== dense conf stream: 8 independent loads per group, branchless ======
        __shared__ double s_red[8];
        const int bid = (int)blockIdx.x - kNB;          // 0..2047
        const float4* __restrict__ p4 = (const float4*)pred;
        const int t0 = bid * 256 + tid;                 // < kStride
        const int r0 = (4 * t0) % 26;
        float sp = 0.0f;
        int prop = 0;

        // 18*k mod 26 for k=0..16 (compile-time)
        constexpr int OFF[17] = {0,18,10,2,20,12,4,22,14,6,24,16,8,0,18,10,2};

        #pragma unroll
        for (int g = 0; g < 2; ++g) {
            const int base = t0 + (8 * g) * kStride;
            float4 v[8];
            #pragma unroll
            for (int j = 0; j < 8; ++j) v[j] = p4[base + j * kStride];
            #pragma unroll
            for (int j = 0; j < 8; ++j) {
                int rk = r0 + OFF[8 * g + j];
                rk = (rk >= 26) ? rk - 26 : rk;
                conf_step(v[j], rk, sp, prop);
            }
        }
        // tail: k=16 (only first TOT_F4 - 16*kStride threads)
        {
            const int idx = t0 + 16 * kStride;
            if (idx < TOT_F4) {
                int rt = r0 + OFF[16];
                rt = (rt >= 26) ? rt - 26 : rt;
                conf_step(p4[idx], rt, sp, prop);
            }
        }

        double spd = wave_sum((double)sp);
        double prd = wave_sum((double)prop);
        int wid = tid >> 6;
        if ((tid & 63) == 0) { s_red[wid] = spd; s_red[4 + wid] = prd; }
        __syncthreads();
        if (tid == 0) {
            ws[bid]                = s_red[0] + s_red[1] + s_red[2] + s_red[3];
            ws[DENSE_BLOCKS + bid] = s_red[4] + s_red[5] + s_red[6] + s_red[7];
        }
        return;
    }

    // ================= sparse targets part (one block per batch) =================
    const int b = blockIdx.x;
    __shared__ float s_t[kMaxT][kRowW];
    __shared__ float s_aw[kNA], s_ah[kNA];
    __shared__ int s_cell[kMaxT], s_bn[kMaxT], s_zm[kMaxT], s_valid[kMaxT];
    __shared__ int s_label[kMaxT];
    __shared__ float s_tx[kMaxT], s_ty[kMaxT], s_tw[kMaxT], s_th[kMaxT];

    for (int i = tid; i < kMaxT * kRowW; i += 256)
        ((float*)s_t)[i] = target[(long long)b * kMaxT * kRowW + i];
    if (tid < kNA) {
        s_aw[tid] = anchors[tid * 2 + 0] / 8.0f;
        s_ah[tid] = anchors[tid * 2 + 1] / 8.0f;
    }
    __syncthreads();

    const int tsz = tsizes[b];
    double ngt = 0.0, ncorr = 0.0;
    int myCell = -1;

    if (tid < kMaxT) {
        const float* row = s_t[tid];
        float gx = row[0] / 8.0f, gy = row[1] / 8.0f;
        float gh = row[3] / 8.0f, gw = row[4] / 8.0f;
        int valid = (tid < tsz) && (gw != 0.0f) && (gh != 0.0f);
        int gi = min(max((int)gx, 0), kNW - 1);
        int gj = min(max((int)gy, 0), kNH - 1);

        float best = -1.0f; int bn = 0; int zm = 0;
        #pragma unroll
        for (int a = 0; a < kNA; ++a) {
            float aw = s_aw[a], ah = s_ah[a];
            float inter = fmaxf(fminf(gw, aw) + 1.0f, 0.0f) * fmaxf(fminf(gh, ah) + 1.0f, 0.0f);
            float iou = inter / ((gw + 1.0f) * (gh + 1.0f) + (aw + 1.0f) * (ah + 1.0f) - inter + 1e-16f);
            if (iou > best) { best = iou; bn = a; }
            if (iou > 0.5f) zm |= (1 << a);
        }

        int lab = 0; float lbest = row[13];
        #pragma unroll
        for (int c = 1; c < kNC; ++c)
            if (row[13 + c] > lbest) { lbest = row[13 + c]; lab = c; }

        long long base = ((((long long)b * kNA + bn) * kNH + gj) * kNW + gi) * kCH;
        float pc = pred[base + 0];
        float px = tanhf(pred[base + 1]) + 0.5f + (float)gi;
        float py = tanhf(pred[base + 2]) + 0.5f + (float)gj;
        float ph = expf(pred[base + 4]) * s_ah[bn];
        float pw = expf(pred[base + 5]) * s_aw[bn];
        float b1x1 = gx - gw, b1x2 = gx + gw, b1y1 = gy - gh, b1y2 = gy + gh;
        float b2x1 = px - pw, b2x2 = px + pw, b2y1 = py - ph, b2y2 = py + ph;
        float iw = fmaxf(fminf(b1x2, b2x2) - fmaxf(b1x1, b2x1) + 1.0f, 0.0f);
        float ih = fmaxf(fminf(b1y2, b2y2) - fmaxf(b1y1, b2y1) + 1.0f, 0.0f);
        float inter2 = iw * ih;
        float a1 = (b1x2 - b1x1 + 1.0f) * (b1y2 - b1y1 + 1.0f);
        float a2 = (b2x2 - b2x1 + 1.0f) * (b2y2 - b2y1 + 1.0f);
        float iou2 = inter2 / (a1 + a2 - inter2 + 1e-16f);
        int plab = 0; float pbest = pred[base + 6];
        #pragma unroll
        for (int c = 1; c < kNC; ++c) {
            float v = pred[base + 6 + c];
            if (v > pbest) { pbest = v; plab = c; }
        }
        int correct = valid && (iou2 > 0.5f) && (plab == lab) && (pc > 0.0f);

        myCell = gj * kNW + gi;
        s_cell[tid] = myCell; s_bn[tid] = bn; s_zm[tid] = zm; s_valid[tid] = valid;
        s_label[tid] = lab;
        s_tx[tid] = inv_tanhf(gx - ((float)gi + 0.5f));
        s_ty[tid] = inv_tanhf(gy - ((float)gj + 0.5f));
        s_tw[tid] = logf(gw / s_aw[bn] + 1e-16f);
        s_th[tid] = logf(gh / s_ah[bn] + 1e-16f);
        ngt = (double)valid; ncorr = (double)correct;
    }
    __syncthreads();

    // lane-parallel last-writer-wins resolution
    double S_excl = 0, cnt_excl = 0, nM = 0, bce = 0;
    double sx = 0, sy = 0, sw_ = 0, sh_ = 0, ce = 0;

    if (tid < kMaxT) {
        int lastTouch[kNA], lastSet[kNA], lastCm[kNA];
        #pragma unroll
        for (int a = 0; a < kNA; ++a) { lastTouch[a] = -1; lastSet[a] = -1; lastCm[a] = 0; }

        for (int tp = 0; tp < kMaxT; ++tp) {
            if (!s_valid[tp] || s_cell[tp] != myCell) continue;
            int bnp = s_bn[tp], zmp = s_zm[tp];
            #pragma unroll
            for (int a = 0; a < kNA; ++a) {
                bool setr = (bnp == a);
                if (setr || ((zmp >> a) & 1)) { lastTouch[a] = tp; lastCm[a] = setr ? 1 : 0; }
                if (setr) lastSet[a] = tp;
            }
        }

        int gj = myCell >> 7, gi = myCell & 127;
        #pragma unroll
        for (int a = 0; a < kNA; ++a) {
            if (lastTouch[a] != tid) continue;          // unique owner per (cell,a)
            bool msk = lastSet[a] >= 0;
            bool cmf = lastCm[a] != 0;
            if (!msk && cmf) continue;
            long long base = ((((long long)b * kNA + a) * kNH + gj) * kNW + gi) * kCH;
            float pc = pred[base];
            float sp2 = softplusf(pc);
            S_excl += (double)sp2; cnt_excl += 1.0;
            if (msk) {
                int ts = lastSet[a];
                nM += 1.0; bce += (double)(sp2 - pc);
                float dx = pred[base + 1] - s_tx[ts];
                float dy = pred[base + 2] - s_ty[ts];
                float dh = pred[base + 4] - s_th[ts];
                float dw = pred[base + 5] - s_tw[ts];
                sx += (double)(dx * dx); sy += (double)(dy * dy);
                sw_ += (double)(dw * dw); sh_ += (double)(dh * dh);
                float m20 = pred[base + 6];
                #pragma unroll
                for (int c = 1; c < kNC; ++c) m20 = fmaxf(m20, pred[base + 6 + c]);
                float es = 0.0f;
                #pragma unroll
                for (int c = 0; c < kNC; ++c) es += expf(pred[base + 6 + c] - m20);
                ce += (double)(m20 + logf(es) - pred[base + 6 + s_label[ts]]);
            }
        }
    }

    if (tid < 64) {
        S_excl = wave_sum(S_excl); cnt_excl = wave_sum(cnt_excl);
        nM = wave_sum(nM); bce = wave_sum(bce);
        sx = wave_sum(sx); sy = wave_sum(sy); sw_ = wave_sum(sw_); sh_ = wave_sum(sh_);
        ce = wave_sum(ce); ngt = wave_sum(ngt); ncorr = wave_sum(ncorr);
        if (tid == 0) {
            double* o = &ws[SP_BASE + b * SP_N];
            o[0] = S_excl; o[1] = cnt_excl; o[2] = nM; o[3] = bce;
            o[4] = sx; o[5] = sy; o[6] = sw_; o[7] = sh_;
            o[8] = ce; o[9] = ngt; o[10] = ncorr;
        }
    }
}

extern "C" __global__ __launch_bounds__(256)
void yolo_finalize(const double* __restrict__ ws, float* __restrict__ out) {
    __shared__ double s_red[8];
    __shared__ double s_sp[kNB * SP_N];
    __shared__ double s_acc[SP_N];
    const int tid = threadIdx.x;

    // parallel stage of sparse partials
    if (tid < kNB * SP_N) s_sp[tid] = ws[SP_BASE + tid];

    double sp = 0.0, pr = 0.0;
    for (int i = tid; i < DENSE_BLOCKS; i += 256) {
        sp += ws[i];
        pr += ws[DENSE_BLOCKS + i];
    }
    sp = wave_sum(sp); pr = wave_sum(pr);
    int wid = tid >> 6;
    if ((tid & 63) == 0) { s_red[wid] = sp; s_red[4 + wid] = pr; }
    __syncthreads();

    if (tid < SP_N) {   // lane j sums its accumulator over 16 batches
        double acc = 0.0;
        #pragma unroll
        for (int b = 0; b < kNB; ++b) acc += s_sp[b * SP_N + tid];
        s_acc[tid] = acc;
    }
    __syncthreads();

    if (tid == 0) {
        double S_all = s_red[0] + s_red[1] + s_red[2] + s_red[3];
        double nProp = s_red[4] + s_red[5] + s_red[6] + s_red[7];
        double S_excl = s_acc[0], cnt_excl = s_acc[1];
        double nMc = s_acc[2], bce = s_acc[3];
        double sx = s_acc[4], sy = s_acc[5], sw = s_acc[6], sh = s_acc[7];
        double ce = s_acc[8], nGT = s_acc[9], nCorr = s_acc[10];
        double nM = fmax(nMc, 1.0);
        double nF = fmax((double)kNTot - cnt_excl, 1.0);
        double loss_conf = 1.25 * (S_all - S_excl) / nF + bce / nM;
        double loss = (sx + sy + sw + sh) / nM + loss_conf + (ce / nM) / 16.0;
        double recall = (nGT > 0.0) ? nCorr / fmax(nGT, 1.0) : 1.0;
        double precision = (nProp > 0.0) ? nCorr / fmax(nProp, 1.0) : 1.0;
        out[0] = (float)loss;
        out[1] = (float)recall;
        out[2] = (float)precision;
    }
}

extern "C" void kernel_launch(void* const* d_in, const int* in_sizes, int n_in,
                              void* d_out, int out_size, void* d_ws, size_t ws_size,
                              hipStream_t stream) {
    const float* pred    = (const float*)d_in[0];
    const float* target  = (const float*)d_in[1];
    const int*   tsizes  = (const int*)d_in[2];
    const float* anchors = (const float*)d_in[3];
    float* out = (float*)d_out;
    double* ws = (double*)d_ws;

    yolo_main<<<DENSE_BLOCKS + kNB, 256, 0, stream>>>(pred, target, tsizes, anchors, ws);
    yolo_finalize<<<1, 256, 0, stream>>>(ws, out);
}